// Round 9
// baseline (1490.425 us; speedup 1.0000x reference)
//
#include <hip/hip_runtime.h>
#include <math.h>

// Problem constants: T=2048, B=256, H=128, IN_DIM=1, NUM_DATA=4096
#define T_STEPS 2048
#define BATCH   256
#define HDIM    128

__device__ __forceinline__ float fast_rcp(float x) { return __builtin_amdgcn_rcpf(x); }
__device__ __forceinline__ float sigmoid_f(float x) { return fast_rcp(1.0f + __expf(-x)); }
__device__ __forceinline__ float tanh_f(float x) {
    float e = __expf(2.0f * x);
    return 1.0f - 2.0f * fast_rcp(e + 1.0f);
}

#define REP8(M) M(0) M(1) M(2) M(3) M(4) M(5) M(6) M(7)

// R29 = R22 (verified 1126us, absmax 0.0) + DETERMINISTIC INTRA-BARRIER
// SKEW: waves 4-7 (the second wave on each SIMD: wave w and w+4 share SIMD
// w&3) run 192cy of s_nop at the top of every step, right after the
// barrier. In lockstep the two waves' exposed-latency windows (post-barrier
// LDS read ~120cy, tail hazard gaps ~150cy) coincide and are fully
// exposed; the skew makes wave B's read+GEMV overlap wave A's tail chain,
// so each wave's GEMV runs near solo issue rate. R28's flag-sync attempt
// failed because the crew dependency is symmetric (skew -> spin-wait,
// +LDS-poll latency, one 32ms livelock outlier); this keeps the hardware
// barrier (deterministic, race-free) and only de-aligns execution.
// Worst case is bounded: +192cy/step. Output bit-identical to R22.
// Everything below except the crewv plumbing + skew block is R22 verbatim.
__global__ __launch_bounds__(512, 2)
void lstm_seq_kernel(const int*   __restrict__ label,
                     const float* __restrict__ h0,     // (1, 4096, 128)
                     const float* __restrict__ W_ih,   // (512, 1)
                     const float* __restrict__ W_hh,   // (512, 128)
                     const float* __restrict__ b_ih,   // (512,)
                     const float* __restrict__ b_hh,   // (512,)
                     const float* __restrict__ W_lin,  // (1, 128)
                     const float* __restrict__ b_lin,  // (1,)
                     float*       __restrict__ out)    // (T, B, 1)
{
    const int tid   = threadIdx.x;
    const int batch = blockIdx.x;
    const int m     = tid >> 2;     // h element 0..127 (also flush t-slot j)
    const int q     = tid & 3;      // K-quarter 0..3
    const int q8    = q * 8;

    const int ri = m, rf = m + 128, rg = m + 256, ro = m + 384;

    // 128 slots x 144 words = 73728 B. Slot k holds h_state_{k+1}.
    // Slot 127 doubles as h_init scratch for the C prologue.
    __shared__ __attribute__((aligned(16))) float hist[128 * 144];

    const float4* W4 = (const float4*)W_hh;
    const float4* L4 = (const float4*)W_lin;

    // ---- C-side load + fold (used only for step 0, UNSCALED) ----
    #define DECL_W(i) \
        float4 wi##i = W4[ri * 32 + q8 + (i)]; \
        float4 wf##i = W4[rf * 32 + q8 + (i)]; \
        float4 wg##i = W4[rg * 32 + q8 + (i)]; \
        float4 wo##i = W4[ro * 32 + q8 + (i)];
    REP8(DECL_W)

    const float wih_i = W_ih[ri], wih_f = W_ih[rf];
    const float wih_g = W_ih[rg], wih_o = W_ih[ro];
    const float blin  = b_lin[0];

    const float bi_ = b_ih[ri] + b_hh[ri] + wih_i * blin;
    const float bf_ = b_ih[rf] + b_hh[rf] + wih_f * blin;
    const float bg_ = b_ih[rg] + b_hh[rg] + wih_g * blin;
    const float bo_ = b_ih[ro] + b_hh[ro] + wih_o * blin;

    // scaled quarter-seed biases (gate-named): s_gate * bias / 4.
    // Constants BIT-IDENTICAL to the asm literals:
    //   -log2e = 0xBFB8AA3B = -0x1.715476p+0f ; 2log2e = 0x4038AA3B.
    const float SNEG = -0x1.715476p+0f;
    const float SG   =  0x1.715476p+1f;
    const float sI = bi_ * 0.25f * SNEG;
    const float sF = bf_ * 0.25f * SNEG;
    const float sG_ = bg_ * 0.25f * SG;
    const float sO = bo_ * 0.25f * SNEG;

    // ---- gate-XOR permutation: slot p on lane q holds gate (p^q) ----
    const float b0s = (q==0)?sI :(q==1)?sF :(q==2)?sG_:sO;   // gate q
    const float b1s = (q==0)?sF :(q==1)?sI :(q==2)?sO :sG_;  // gate q^1
    const float b2s = (q==0)?sG_:(q==1)?sO :(q==2)?sI :sF;   // gate q^2
    const float b3s = (q==0)?sO :(q==1)?sG_:(q==2)?sF :sI;   // gate q^3
    const float wihA = (q==0)?wih_i:(q==1)?wih_f:(q==2)?wih_g:wih_o;
    const float wihB = (q==0)?wih_f:(q==1)?wih_i:(q==2)?wih_o:wih_g;
    const float wihC = (q==0)?wih_g:(q==1)?wih_o:(q==2)?wih_i:wih_f;
    const float wihD = (q==0)?wih_o:(q==1)?wih_g:(q==2)?wih_f:wih_i;
    const float sc0 = ( q     == 2) ? SG : SNEG;
    const float sc1 = ((q^1)  == 2) ? SG : SNEG;
    const float sc2 = ((q^2)  == 2) ? SG : SNEG;
    const float sc3 = ((q^3)  == 2) ? SG : SNEG;
    // per-lane activation finisher: sigmoid a=r ; tanh a=-2r+1
    const float caq = (q==2) ? -2.0f : 1.0f;
    const float cbq = (q==2) ?  1.0f : 0.0f;

    #define FOLD_W(i) { float4 lv = L4[q8 + (i)]; \
        wi##i.x = fmaf(wih_i, lv.x, wi##i.x); wi##i.y = fmaf(wih_i, lv.y, wi##i.y); \
        wi##i.z = fmaf(wih_i, lv.z, wi##i.z); wi##i.w = fmaf(wih_i, lv.w, wi##i.w); \
        wf##i.x = fmaf(wih_f, lv.x, wf##i.x); wf##i.y = fmaf(wih_f, lv.y, wf##i.y); \
        wf##i.z = fmaf(wih_f, lv.z, wf##i.z); wf##i.w = fmaf(wih_f, lv.w, wf##i.w); \
        wg##i.x = fmaf(wih_g, lv.x, wg##i.x); wg##i.y = fmaf(wih_g, lv.y, wg##i.y); \
        wg##i.z = fmaf(wih_g, lv.z, wg##i.z); wg##i.w = fmaf(wih_g, lv.w, wg##i.w); \
        wo##i.x = fmaf(wih_o, lv.x, wo##i.x); wo##i.y = fmaf(wih_o, lv.y, wo##i.y); \
        wo##i.z = fmaf(wih_o, lv.z, wo##i.z); wo##i.w = fmaf(wih_o, lv.w, wo##i.w); }
    REP8(FOLD_W)

    const int   lane = tid & 63;
    const int   ya0w = lane + ((lane >> 5) << 2);   // word of h[lane] in a slot
    const float wl_a = W_lin[lane];
    const float wl_b = W_lin[lane + 64];
    const int   hword = m + ((m >> 5) << 2);        // element word in a slot

    // ---- init h into slot 127 (scratch; overwritten at t=127) ----
    float* slotI = &hist[144 * 127];
    if (tid < HDIM) slotI[tid + ((tid >> 5) << 2)] = h0[label[batch] * HDIM + tid];
    __syncthreads();

    // y_init (uniform across waves) for the t=0 bias correction
    float p0 = slotI[ya0w] * wl_a + slotI[ya0w + 72] * wl_b;
    #pragma unroll
    for (int off = 1; off < 64; off <<= 1) p0 += __shfl_xor(p0, off, 64);
    const float y0 = p0 + blin;

    const float cbi = bi_ - wih_i * y0;
    const float cbf = bf_ - wih_f * y0;
    const float cbg = bg_ - wih_g * y0;
    const float cbo = bo_ - wih_o * y0;

    // ---- step 0 in C: read slot 127 (init), write state 1 into slot 0 ----
    const float4* hq0 = (const float4*)(slotI + 36 * q);
    float ai = 0.f, af = 0.f, ag = 0.f, ao = 0.f;
    #define DOT4(i) { float4 hv = hq0[(i)]; \
        ai = fmaf(hv.x, wi##i.x, ai); ai = fmaf(hv.y, wi##i.y, ai); \
        ai = fmaf(hv.z, wi##i.z, ai); ai = fmaf(hv.w, wi##i.w, ai); \
        af = fmaf(hv.x, wf##i.x, af); af = fmaf(hv.y, wf##i.y, af); \
        af = fmaf(hv.z, wf##i.z, af); af = fmaf(hv.w, wf##i.w, af); \
        ag = fmaf(hv.x, wg##i.x, ag); ag = fmaf(hv.y, wg##i.y, ag); \
        ag = fmaf(hv.z, wg##i.z, ag); ag = fmaf(hv.w, wg##i.w, ag); \
        ao = fmaf(hv.x, wo##i.x, ao); ao = fmaf(hv.y, wo##i.y, ao); \
        ao = fmaf(hv.z, wo##i.z, ao); ao = fmaf(hv.w, wo##i.w, ao); }
    REP8(DOT4)
    ai += __shfl_xor(ai, 1, 64); af += __shfl_xor(af, 1, 64);
    ag += __shfl_xor(ag, 1, 64); ao += __shfl_xor(ao, 1, 64);
    ai += __shfl_xor(ai, 2, 64); af += __shfl_xor(af, 2, 64);
    ag += __shfl_xor(ag, 2, 64); ao += __shfl_xor(ao, 2, 64);
    const float iv0 = sigmoid_f(ai + cbi);
    const float fv0 = sigmoid_f(af + cbf);
    const float gv0 = tanh_f  (ag + cbg);
    const float ov0 = sigmoid_f(ao + cbo);
    float c = iv0 * gv0;                 // c_prev = 0
    const float hn0 = ov0 * tanh_f(c);
    if (q == 0) hist[hword] = hn0;       // slot 0 = state 1
    __syncthreads();

    // ---- asm operand prep ----
    const unsigned histB = (unsigned)(unsigned long long)(&hist[0]);
    const unsigned vR0 = histB + 144u * (unsigned)q;           // slot0 quarter
    const unsigned hW0 = histB + 4u * (unsigned)hword;         // write(slot0); early +576 -> slot t
    const unsigned vD0 = (unsigned)(144 * q - 4 * hword);      // read(t) - write(t)
    const unsigned fR0 = histB + 576u * (unsigned)m + 144u * (unsigned)q;
    const unsigned jO0 = 1024u * (unsigned)m;                  // out j*1024
    const unsigned vO0 = 4u * (unsigned)batch;                 // out[0] byte
    // permuted weight-row byte offsets: slot p <- row (m + 128*(q^p))
    const unsigned off0 = (unsigned)((m + 128 * (q    )) * 512 + q * 128);
    const unsigned off1 = (unsigned)((m + 128 * (q ^ 1)) * 512 + q * 128);
    const unsigned off2 = (unsigned)((m + 128 * (q ^ 2)) * 512 + q * 128);
    const unsigned off3 = (unsigned)((m + 128 * (q ^ 3)) * 512 + q * 128);
    const unsigned offL = (unsigned)(q * 128);
    const unsigned crewv = (unsigned)(tid >> 8);   // 0: waves 0-3, 1: waves 4-7

    asm volatile(
        // ---------------- prologue: fixed-reg setup ----------------
        "v_mov_b32 v220, %[b0]\n\t"
        "v_mov_b32 v221, 0\n\t"
        "v_mov_b32 v222, %[b1]\n\t"
        "v_mov_b32 v223, 0\n\t"
        "v_mov_b32 v224, %[b2]\n\t"
        "v_mov_b32 v225, 0\n\t"
        "v_mov_b32 v226, %[b3]\n\t"
        "v_mov_b32 v227, 0\n\t"
        "v_mov_b32 v185, %[blin]\n\t"
        "v_mov_b32 v168, %[c0]\n\t"
        "v_mov_b32 v172, %[vR]\n\t"
        "v_mov_b32 v174, %[hW]\n\t"
        "v_mov_b32 v186, %[vD]\n\t"
        "v_mov_b32 v184, %[fR]\n\t"
        "v_mov_b32 v171, %[jO]\n\t"
        "v_mov_b32 v176, %[vO]\n\t"
        "v_readfirstlane_b32 s29, %[crewv]\n\t"   // SIMD-partner parity
        "s_nop 4\n\t"
        // q==0 store mask (lanes 0,4,8,...) -> s[26:27]
        "s_mov_b32 s26, 0x11111111\n\t"
        "s_mov_b32 s27, 0x11111111\n\t"
        // weights: 8x dwordx4 per slot into fixed quads (gate-permuted rows)
        "global_load_dwordx4 v[32:35], %[off0], %[whh] offset:0\n\t"
        "global_load_dwordx4 v[36:39], %[off0], %[whh] offset:16\n\t"
        "global_load_dwordx4 v[40:43], %[off0], %[whh] offset:32\n\t"
        "global_load_dwordx4 v[44:47], %[off0], %[whh] offset:48\n\t"
        "global_load_dwordx4 v[48:51], %[off0], %[whh] offset:64\n\t"
        "global_load_dwordx4 v[52:55], %[off0], %[whh] offset:80\n\t"
        "global_load_dwordx4 v[56:59], %[off0], %[whh] offset:96\n\t"
        "global_load_dwordx4 v[60:63], %[off0], %[whh] offset:112\n\t"
        "global_load_dwordx4 v[64:67], %[off1], %[whh] offset:0\n\t"
        "global_load_dwordx4 v[68:71], %[off1], %[whh] offset:16\n\t"
        "global_load_dwordx4 v[72:75], %[off1], %[whh] offset:32\n\t"
        "global_load_dwordx4 v[76:79], %[off1], %[whh] offset:48\n\t"
        "global_load_dwordx4 v[80:83], %[off1], %[whh] offset:64\n\t"
        "global_load_dwordx4 v[84:87], %[off1], %[whh] offset:80\n\t"
        "global_load_dwordx4 v[88:91], %[off1], %[whh] offset:96\n\t"
        "global_load_dwordx4 v[92:95], %[off1], %[whh] offset:112\n\t"
        "global_load_dwordx4 v[96:99], %[off2], %[whh] offset:0\n\t"
        "global_load_dwordx4 v[100:103], %[off2], %[whh] offset:16\n\t"
        "global_load_dwordx4 v[104:107], %[off2], %[whh] offset:32\n\t"
        "global_load_dwordx4 v[108:111], %[off2], %[whh] offset:48\n\t"
        "global_load_dwordx4 v[112:115], %[off2], %[whh] offset:64\n\t"
        "global_load_dwordx4 v[116:119], %[off2], %[whh] offset:80\n\t"
        "global_load_dwordx4 v[120:123], %[off2], %[whh] offset:96\n\t"
        "global_load_dwordx4 v[124:127], %[off2], %[whh] offset:112\n\t"
        "global_load_dwordx4 v[128:131], %[off3], %[whh] offset:0\n\t"
        "global_load_dwordx4 v[132:135], %[off3], %[whh] offset:16\n\t"
        "global_load_dwordx4 v[136:139], %[off3], %[whh] offset:32\n\t"
        "global_load_dwordx4 v[140:143], %[off3], %[whh] offset:48\n\t"
        "global_load_dwordx4 v[144:147], %[off3], %[whh] offset:64\n\t"
        "global_load_dwordx4 v[148:151], %[off3], %[whh] offset:80\n\t"
        "global_load_dwordx4 v[152:155], %[off3], %[whh] offset:96\n\t"
        "global_load_dwordx4 v[156:159], %[off3], %[whh] offset:112\n\t"
        // W_lin quarter-slice -> persistent v[188:219]
        "global_load_dwordx4 v[188:191], %[offL], %[wlin] offset:0\n\t"
        "global_load_dwordx4 v[192:195], %[offL], %[wlin] offset:16\n\t"
        "global_load_dwordx4 v[196:199], %[offL], %[wlin] offset:32\n\t"
        "global_load_dwordx4 v[200:203], %[offL], %[wlin] offset:48\n\t"
        "global_load_dwordx4 v[204:207], %[offL], %[wlin] offset:64\n\t"
        "global_load_dwordx4 v[208:211], %[offL], %[wlin] offset:80\n\t"
        "global_load_dwordx4 v[212:215], %[offL], %[wlin] offset:96\n\t"
        "global_load_dwordx4 v[216:219], %[offL], %[wlin] offset:112\n\t"
        "s_waitcnt vmcnt(0)\n\t"
        // fold: W'[slot p] = W + wih(p^q) * W_lin, then pre-scale by that
        // gate's exp2 constant (per-lane VGPR scale).
        ".set K_I, 0\n"
        ".rept 32\n"
        " v_fma_f32 v[32+K_I],  %[wA], v[188+K_I], v[32+K_I]\n"
        " v_fma_f32 v[64+K_I],  %[wB], v[188+K_I], v[64+K_I]\n"
        " v_fma_f32 v[96+K_I],  %[wC], v[188+K_I], v[96+K_I]\n"
        " v_fma_f32 v[128+K_I], %[wD], v[188+K_I], v[128+K_I]\n"
        " .set K_I, K_I+1\n"
        ".endr\n"
        ".set K_I, 0\n"
        ".rept 32\n"
        " v_mul_f32 v[32+K_I],  %[sc0], v[32+K_I]\n"
        " v_mul_f32 v[64+K_I],  %[sc1], v[64+K_I]\n"
        " v_mul_f32 v[96+K_I],  %[sc2], v[96+K_I]\n"
        " v_mul_f32 v[128+K_I], %[sc3], v[128+K_I]\n"
        " .set K_I, K_I+1\n"
        ".endr\n"
        "s_movk_i32 s24, 1\n\t"
        // ---------------- main loop: t = 1 .. 2047 ----------------
        "1:\n\t"
        // ---- per-step skew: waves 4-7 delay 192cy to de-align with their
        //      SIMD partner (wave w and w+4 share SIMD w&3) ----
        "s_cmp_eq_u32 s29, 1\n\t"
        "s_cbranch_scc0 9f\n\t"
        ".rept 24\n s_nop 7\n .endr\n"
        "9:\n\t"
        // h quarter: 8x b128 broadcast reads from slot t-1
        "ds_read_b128 v[0:3],   v172\n\t"
        "ds_read_b128 v[4:7],   v172 offset:16\n\t"
        "ds_read_b128 v[8:11],  v172 offset:32\n\t"
        "ds_read_b128 v[12:15], v172 offset:48\n\t"
        "ds_read_b128 v[16:19], v172 offset:64\n\t"
        "ds_read_b128 v[20:23], v172 offset:80\n\t"
        "ds_read_b128 v[24:27], v172 offset:96\n\t"
        "ds_read_b128 v[28:31], v172 offset:112\n\t"
        // ---- packed GEMV: pairs 0-3 once reads 0-1 land ----
        "s_waitcnt lgkmcnt(6)\n\t"
        "v_pk_fma_f32 v[160:161], v[0:1], v[32:33], v[220:221]\n\t"
        "v_pk_fma_f32 v[162:163], v[0:1], v[64:65], v[222:223]\n\t"
        "v_pk_fma_f32 v[164:165], v[0:1], v[96:97], v[224:225]\n\t"
        "v_pk_fma_f32 v[166:167], v[0:1], v[128:129], v[226:227]\n\t"
        ".set K_I, 2\n"
        ".rept 3\n"
        " v_pk_fma_f32 v[160:161], v[K_I:K_I+1], v[32+K_I:33+K_I], v[160:161]\n"
        " v_pk_fma_f32 v[162:163], v[K_I:K_I+1], v[64+K_I:65+K_I], v[162:163]\n"
        " v_pk_fma_f32 v[164:165], v[K_I:K_I+1], v[96+K_I:97+K_I], v[164:165]\n"
        " v_pk_fma_f32 v[166:167], v[K_I:K_I+1], v[128+K_I:129+K_I], v[166:167]\n"
        " .set K_I, K_I+2\n"
        ".endr\n"
        "s_waitcnt lgkmcnt(4)\n\t"
        ".rept 4\n"
        " v_pk_fma_f32 v[160:161], v[K_I:K_I+1], v[32+K_I:33+K_I], v[160:161]\n"
        " v_pk_fma_f32 v[162:163], v[K_I:K_I+1], v[64+K_I:65+K_I], v[162:163]\n"
        " v_pk_fma_f32 v[164:165], v[K_I:K_I+1], v[96+K_I:97+K_I], v[164:165]\n"
        " v_pk_fma_f32 v[166:167], v[K_I:K_I+1], v[128+K_I:129+K_I], v[166:167]\n"
        " .set K_I, K_I+2\n"
        ".endr\n"
        "s_waitcnt lgkmcnt(2)\n\t"
        ".rept 4\n"
        " v_pk_fma_f32 v[160:161], v[K_I:K_I+1], v[32+K_I:33+K_I], v[160:161]\n"
        " v_pk_fma_f32 v[162:163], v[K_I:K_I+1], v[64+K_I:65+K_I], v[162:163]\n"
        " v_pk_fma_f32 v[164:165], v[K_I:K_I+1], v[96+K_I:97+K_I], v[164:165]\n"
        " v_pk_fma_f32 v[166:167], v[K_I:K_I+1], v[128+K_I:129+K_I], v[166:167]\n"
        " .set K_I, K_I+2\n"
        ".endr\n"
        "s_waitcnt lgkmcnt(0)\n\t"
        ".rept 4\n"
        " v_pk_fma_f32 v[160:161], v[K_I:K_I+1], v[32+K_I:33+K_I], v[160:161]\n"
        " v_pk_fma_f32 v[162:163], v[K_I:K_I+1], v[64+K_I:65+K_I], v[162:163]\n"
        " v_pk_fma_f32 v[164:165], v[K_I:K_I+1], v[96+K_I:97+K_I], v[164:165]\n"
        " v_pk_fma_f32 v[166:167], v[K_I:K_I+1], v[128+K_I:129+K_I], v[166:167]\n"
        " .set K_I, K_I+2\n"
        ".endr\n"
        // ---- collapse lo+hi: slot sums S0..S3 (slot p = gate p^q) ----
        "v_add_f32 v160, v160, v161\n\t"
        "v_add_f32 v161, v162, v163\n\t"
        "v_add_f32 v164, v164, v165\n\t"
        "v_add_f32 v165, v166, v167\n\t"
        // ---- 3-DPP gate butterfly: v160 <- FULL sum of gate q on lane q ----
        "s_nop 1\n\t"
        "v_add_f32_dpp v160, v161, v160 quad_perm:[1,0,3,2] row_mask:0xf bank_mask:0xf\n\t"
        "v_add_f32_dpp v164, v165, v164 quad_perm:[1,0,3,2] row_mask:0xf bank_mask:0xf\n\t"
        // ptr advance fills the DPP gap: v174 -> write(t), v172 -> read(t)
        "v_add_u32 v174, 0x240, v174\n\t"
        "v_add_u32 v172, v174, v186\n\t"
        "s_nop 1\n\t"
        "v_add_f32_dpp v160, v164, v160 quad_perm:[2,3,0,1] row_mask:0xf bank_mask:0xf\n\t"
        // ---- single activation path (values pre-scaled for exp2) ----
        "s_nop 3\n\t"
        "v_exp_f32 v160, v160\n\t"
        "s_nop 1\n\t"
        "v_add_f32 v160, 1.0, v160\n\t"
        "v_rcp_f32 v160, v160\n\t"
        "s_nop 1\n\t"
        "v_fma_f32 v166, %[ca], v160, %[cb]\n\t"   // a = sigmoid / tanh of gate q
        // ---- quad redistribute: t1 = i*g (lane0), t2 = f, t3 = o ----
        "s_nop 3\n\t"
        "v_mul_f32_dpp v161, v166, v166 quad_perm:[2,3,0,1] row_mask:0xf bank_mask:0xf\n\t"
        "v_mov_b32_dpp v162, v166 quad_perm:[1,0,3,2] row_mask:0xf bank_mask:0xf\n\t"
        "v_mov_b32_dpp v165, v166 quad_perm:[3,3,3,3] row_mask:0xf bank_mask:0xf\n\t"
        "s_nop 2\n\t"
        "v_fma_f32 v168, v162, v168, v161\n\t"     // c = f*c + i*g  (lane0 exact)
        // tanh(c) with explicit wait states
        "v_mul_f32 v163, 0x4038aa3b, v168\n\t"
        "v_exp_f32 v163, v163\n\t"
        "s_nop 1\n\t"
        "v_add_f32 v163, 1.0, v163\n\t"
        "v_rcp_f32 v163, v163\n\t"
        "s_nop 1\n\t"
        "v_fma_f32 v163, -2.0, v163, 1.0\n\t"
        "v_mul_f32 v169, v165, v163\n\t"           // hn = o * tanh(c)
        // publish h into ring slot t (q==0 lanes; v174 already advanced)
        "s_mov_b64 s[22:23], exec\n\t"
        "s_mov_b64 exec, s[26:27]\n\t"
        "ds_write_b32 v174, v169\n\t"
        "s_mov_b64 exec, s[22:23]\n\t"
        "s_waitcnt lgkmcnt(0)\n\t"
        "s_barrier\n\t"
        // ---- flush every 128 steps: out[...] = hist[j].WL + blin ----
        "s_and_b32 s20, s24, 127\n\t"
        "s_cmp_lg_u32 s20, 127\n\t"
        "s_cbranch_scc1 3f\n\t"
        "v_add_u32 v174, 0xfffee000, v174\n\t"   // write base wrap: -73728
        "ds_read_b128 v[0:3],   v184\n\t"
        "ds_read_b128 v[4:7],   v184 offset:16\n\t"
        "ds_read_b128 v[8:11],  v184 offset:32\n\t"
        "ds_read_b128 v[12:15], v184 offset:48\n\t"
        "ds_read_b128 v[16:19], v184 offset:64\n\t"
        "ds_read_b128 v[20:23], v184 offset:80\n\t"
        "ds_read_b128 v[24:27], v184 offset:96\n\t"
        "ds_read_b128 v[28:31], v184 offset:112\n\t"
        "v_mov_b32 v164, 0\n\t"
        "s_waitcnt lgkmcnt(0)\n\t"
        ".set K_I, 0\n"
        ".rept 32\n"
        " v_fma_f32 v164, v[0+K_I], v[188+K_I], v164\n"
        " .set K_I, K_I+1\n"
        ".endr\n"
        "s_nop 1\n\t"
        "v_add_f32_dpp v164, v164, v164 quad_perm:[1,0,3,2] row_mask:0xf bank_mask:0xf\n\t"
        "s_nop 1\n\t"
        "v_add_f32_dpp v164, v164, v164 quad_perm:[2,3,0,1] row_mask:0xf bank_mask:0xf\n\t"
        "v_add_f32 v164, v164, v185\n\t"         // + b_lin
        "v_add_u32 v170, v176, v171\n\t"         // out byte = base + j*1024
        "s_mov_b64 s[22:23], exec\n\t"
        "s_mov_b64 exec, s[26:27]\n\t"
        "global_store_dword v170, v164, %[outp]\n\t"
        "s_mov_b64 exec, s[22:23]\n\t"
        "v_add_u32 v176, 0x20000, v176\n\t"      // out base += 128*256*4
        "s_barrier\n\t"                           // protect hist vs next iter
        "3:\n\t"
        "s_add_i32 s24, s24, 1\n\t"
        "s_cmp_lt_i32 s24, 2048\n\t"
        "s_cbranch_scc1 1b\n\t"
        :
        : [off0]"v"(off0), [off1]"v"(off1), [off2]"v"(off2), [off3]"v"(off3),
          [offL]"v"(offL), [whh]"s"(W_hh), [wlin]"s"(W_lin), [outp]"s"(out),
          [wA]"v"(wihA), [wB]"v"(wihB), [wC]"v"(wihC), [wD]"v"(wihD),
          [b0]"v"(b0s), [b1]"v"(b1s), [b2]"v"(b2s), [b3]"v"(b3s),
          [sc0]"v"(sc0), [sc1]"v"(sc1), [sc2]"v"(sc2), [sc3]"v"(sc3),
          [ca]"v"(caq), [cb]"v"(cbq),
          [blin]"s"(blin), [c0]"v"(c),
          [vR]"v"(vR0), [hW]"v"(hW0), [vD]"v"(vD0), [fR]"v"(fR0),
          [jO]"v"(jO0), [vO]"s"(vO0), [crewv]"v"(crewv)
        : "memory", "scc", "vcc", "s20","s21","s22","s23","s24","s25","s26","s27",
          "s28","s29",
          "v0","v1","v2","v3","v4","v5","v6","v7","v8","v9",
          "v10","v11","v12","v13","v14","v15","v16","v17","v18","v19",
          "v20","v21","v22","v23","v24","v25","v26","v27","v28","v29",
          "v30","v31","v32","v33","v34","v35","v36","v37","v38","v39",
          "v40","v41","v42","v43","v44","v45","v46","v47","v48","v49",
          "v50","v51","v52","v53","v54","v55","v56","v57","v58","v59",
          "v60","v61","v62","v63","v64","v65","v66","v67","v68","v69",
          "v70","v71","v72","v73","v74","v75","v76","v77","v78","v79",
          "v80","v81","v82","v83","v84","v85","v86","v87","v88","v89",
          "v90","v91","v92","v93","v94","v95","v96","v97","v98","v99",
          "v100","v101","v102","v103","v104","v105","v106","v107","v108","v109",
          "v110","v111","v112","v113","v114","v115","v116","v117","v118","v119",
          "v120","v121","v122","v123","v124","v125","v126","v127","v128","v129",
          "v130","v131","v132","v133","v134","v135","v136","v137","v138","v139",
          "v140","v141","v142","v143","v144","v145","v146","v147","v148","v149",
          "v150","v151","v152","v153","v154","v155","v156","v157","v158","v159",
          "v160","v161","v162","v163","v164","v165","v166","v167","v168","v169",
          "v170","v171","v172","v173","v174","v175","v176","v177","v178","v179",
          "v180","v181","v182","v183","v184","v185","v186","v187","v188","v189",
          "v190","v191","v192","v193","v194","v195","v196","v197","v198","v199",
          "v200","v201","v202","v203","v204","v205","v206","v207","v208","v209",
          "v210","v211","v212","v213","v214","v215","v216","v217","v218","v219",
          "v220","v221","v222","v223","v224","v225","v226","v227");
    // no C epilogue: flush k=15 covers out[1920..2047]
}

extern "C" void kernel_launch(void* const* d_in, const int* in_sizes, int n_in,
                              void* d_out, int out_size, void* d_ws, size_t ws_size,
                              hipStream_t stream) {
    // inputs: 0 input (unused), 1 label, 2 h0, 3 W_ih, 4 W_hh,
    //         5 b_ih, 6 b_hh, 7 W_lin, 8 b_lin
    const int*   label = (const int*)  d_in[1];
    const float* h0    = (const float*)d_in[2];
    const float* W_ih  = (const float*)d_in[3];
    const float* W_hh  = (const float*)d_in[4];
    const float* b_ih  = (const float*)d_in[5];
    const float* b_hh  = (const float*)d_in[6];
    const float* W_lin = (const float*)d_in[7];
    const float* b_lin = (const float*)d_in[8];
    float* out = (float*)d_out;

    lstm_seq_kernel<<<dim3(BATCH), dim3(512), 0, stream>>>(
        label, h0, W_ih, W_hh, b_ih, b_hh, W_lin, b_lin, out);
}

// Round 11
// 1125.362 us; speedup vs baseline: 1.3244x; 1.3244x over previous
//
#include <hip/hip_runtime.h>
#include <math.h>

// Problem constants: T=2048, B=256, H=128, IN_DIM=1, NUM_DATA=4096
#define T_STEPS 2048
#define BATCH   256
#define HDIM    128

__device__ __forceinline__ float fast_rcp(float x) { return __builtin_amdgcn_rcpf(x); }
__device__ __forceinline__ float sigmoid_f(float x) { return fast_rcp(1.0f + __expf(-x)); }
__device__ __forceinline__ float tanh_f(float x) {
    float e = __expf(2.0f * x);
    return 1.0f - 2.0f * fast_rcp(e + 1.0f);
}

#define REP8(M) M(0) M(1) M(2) M(3) M(4) M(5) M(6) M(7)

// R31 = R22 VERBATIM RESTORATION (verified 1126.29us, absmax 0.0, the
// session best). R23-R30 tested every structural attack on the ~610cy
// lockstep stall -- 2-batch/block, 4-wave/SIMD, f16 dot2, flag de-phasing
// (2x), barrier skew, 1-wave/SIMD fat registers -- and all regressed or
// failed (R30: inline asm cannot name v256+; 1-wave/SIMD needs AGPR
// operands, unverified). The kernel is latency-bound on the serial
// recurrence chain (57% VALUBusy, 0.17% HBM); R22 stands as the optimum.
//
// R22 = R20 (folded activation pre-scales, pk_fma GEMV, staggered lgkmcnt)
// + GATE-XOR-PERMUTED ACCUMULATORS: lane q accumulates gate (p^q) in acc
// slot p (permutation applied via per-lane load addresses / wih folds /
// scale consts / bias seeds -- zero extra loop cost):
//   4 collapse adds + 3-DPP butterfly  -> full gate-q sum on lane q
//   ONE exp + ONE rcp + fma(CA,r,CB)   -> sigmoid (q!=2) or tanh (q==2)
//   3 quad_perm moves redistribute i*g / f / o for the c,h update.
// Trans ops per wave-iter: 10 -> 4. c on lanes q!=0 is bounded garbage,
// never read. Pointer advance sits in the DPP hazard gap (ds_write_b32
// targets the already-advanced v174; hW0/vD0 shifted accordingly).
// Register map: h v[0:31], slot0 w v[32:63], slot1 w v[64:95],
// slot2 w v[96:127], slot3 w v[128:159], acc pairs v[160:167], c v168,
// hn v169, tmp v170, jO v171, rdaddr v172, wraddr v174, outbase v176,
// flushrd v184, blin v185, vD v186, W_lin v[188:219], seed pairs v[220:227].
__global__ __launch_bounds__(512, 2)
void lstm_seq_kernel(const int*   __restrict__ label,
                     const float* __restrict__ h0,     // (1, 4096, 128)
                     const float* __restrict__ W_ih,   // (512, 1)
                     const float* __restrict__ W_hh,   // (512, 128)
                     const float* __restrict__ b_ih,   // (512,)
                     const float* __restrict__ b_hh,   // (512,)
                     const float* __restrict__ W_lin,  // (1, 128)
                     const float* __restrict__ b_lin,  // (1,)
                     float*       __restrict__ out)    // (T, B, 1)
{
    const int tid   = threadIdx.x;
    const int batch = blockIdx.x;
    const int m     = tid >> 2;     // h element 0..127 (also flush t-slot j)
    const int q     = tid & 3;      // K-quarter 0..3
    const int q8    = q * 8;

    const int ri = m, rf = m + 128, rg = m + 256, ro = m + 384;

    // 128 slots x 144 words = 73728 B. Slot k holds h_state_{k+1}.
    // Slot 127 doubles as h_init scratch for the C prologue.
    __shared__ __attribute__((aligned(16))) float hist[128 * 144];

    const float4* W4 = (const float4*)W_hh;
    const float4* L4 = (const float4*)W_lin;

    // ---- C-side load + fold (used only for step 0, UNSCALED) ----
    #define DECL_W(i) \
        float4 wi##i = W4[ri * 32 + q8 + (i)]; \
        float4 wf##i = W4[rf * 32 + q8 + (i)]; \
        float4 wg##i = W4[rg * 32 + q8 + (i)]; \
        float4 wo##i = W4[ro * 32 + q8 + (i)];
    REP8(DECL_W)

    const float wih_i = W_ih[ri], wih_f = W_ih[rf];
    const float wih_g = W_ih[rg], wih_o = W_ih[ro];
    const float blin  = b_lin[0];

    const float bi_ = b_ih[ri] + b_hh[ri] + wih_i * blin;
    const float bf_ = b_ih[rf] + b_hh[rf] + wih_f * blin;
    const float bg_ = b_ih[rg] + b_hh[rg] + wih_g * blin;
    const float bo_ = b_ih[ro] + b_hh[ro] + wih_o * blin;

    // scaled quarter-seed biases (gate-named): s_gate * bias / 4.
    // Constants BIT-IDENTICAL to the asm literals:
    //   -log2e = 0xBFB8AA3B = -0x1.715476p+0f ; 2log2e = 0x4038AA3B.
    const float SNEG = -0x1.715476p+0f;
    const float SG   =  0x1.715476p+1f;
    const float sI = bi_ * 0.25f * SNEG;
    const float sF = bf_ * 0.25f * SNEG;
    const float sG_ = bg_ * 0.25f * SG;
    const float sO = bo_ * 0.25f * SNEG;

    // ---- gate-XOR permutation: slot p on lane q holds gate (p^q) ----
    const float b0s = (q==0)?sI :(q==1)?sF :(q==2)?sG_:sO;   // gate q
    const float b1s = (q==0)?sF :(q==1)?sI :(q==2)?sO :sG_;  // gate q^1
    const float b2s = (q==0)?sG_:(q==1)?sO :(q==2)?sI :sF;   // gate q^2
    const float b3s = (q==0)?sO :(q==1)?sG_:(q==2)?sF :sI;   // gate q^3
    const float wihA = (q==0)?wih_i:(q==1)?wih_f:(q==2)?wih_g:wih_o;
    const float wihB = (q==0)?wih_f:(q==1)?wih_i:(q==2)?wih_o:wih_g;
    const float wihC = (q==0)?wih_g:(q==1)?wih_o:(q==2)?wih_i:wih_f;
    const float wihD = (q==0)?wih_o:(q==1)?wih_g:(q==2)?wih_f:wih_i;
    const float sc0 = ( q     == 2) ? SG : SNEG;
    const float sc1 = ((q^1)  == 2) ? SG : SNEG;
    const float sc2 = ((q^2)  == 2) ? SG : SNEG;
    const float sc3 = ((q^3)  == 2) ? SG : SNEG;
    // per-lane activation finisher: sigmoid a=r ; tanh a=-2r+1
    const float caq = (q==2) ? -2.0f : 1.0f;
    const float cbq = (q==2) ?  1.0f : 0.0f;

    #define FOLD_W(i) { float4 lv = L4[q8 + (i)]; \
        wi##i.x = fmaf(wih_i, lv.x, wi##i.x); wi##i.y = fmaf(wih_i, lv.y, wi##i.y); \
        wi##i.z = fmaf(wih_i, lv.z, wi##i.z); wi##i.w = fmaf(wih_i, lv.w, wi##i.w); \
        wf##i.x = fmaf(wih_f, lv.x, wf##i.x); wf##i.y = fmaf(wih_f, lv.y, wf##i.y); \
        wf##i.z = fmaf(wih_f, lv.z, wf##i.z); wf##i.w = fmaf(wih_f, lv.w, wf##i.w); \
        wg##i.x = fmaf(wih_g, lv.x, wg##i.x); wg##i.y = fmaf(wih_g, lv.y, wg##i.y); \
        wg##i.z = fmaf(wih_g, lv.z, wg##i.z); wg##i.w = fmaf(wih_g, lv.w, wg##i.w); \
        wo##i.x = fmaf(wih_o, lv.x, wo##i.x); wo##i.y = fmaf(wih_o, lv.y, wo##i.y); \
        wo##i.z = fmaf(wih_o, lv.z, wo##i.z); wo##i.w = fmaf(wih_o, lv.w, wo##i.w); }
    REP8(FOLD_W)

    const int   lane = tid & 63;
    const int   ya0w = lane + ((lane >> 5) << 2);   // word of h[lane] in a slot
    const float wl_a = W_lin[lane];
    const float wl_b = W_lin[lane + 64];
    const int   hword = m + ((m >> 5) << 2);        // element word in a slot

    // ---- init h into slot 127 (scratch; overwritten at t=127) ----
    float* slotI = &hist[144 * 127];
    if (tid < HDIM) slotI[tid + ((tid >> 5) << 2)] = h0[label[batch] * HDIM + tid];
    __syncthreads();

    // y_init (uniform across waves) for the t=0 bias correction
    float p0 = slotI[ya0w] * wl_a + slotI[ya0w + 72] * wl_b;
    #pragma unroll
    for (int off = 1; off < 64; off <<= 1) p0 += __shfl_xor(p0, off, 64);
    const float y0 = p0 + blin;

    const float cbi = bi_ - wih_i * y0;
    const float cbf = bf_ - wih_f * y0;
    const float cbg = bg_ - wih_g * y0;
    const float cbo = bo_ - wih_o * y0;

    // ---- step 0 in C: read slot 127 (init), write state 1 into slot 0 ----
    const float4* hq0 = (const float4*)(slotI + 36 * q);
    float ai = 0.f, af = 0.f, ag = 0.f, ao = 0.f;
    #define DOT4(i) { float4 hv = hq0[(i)]; \
        ai = fmaf(hv.x, wi##i.x, ai); ai = fmaf(hv.y, wi##i.y, ai); \
        ai = fmaf(hv.z, wi##i.z, ai); ai = fmaf(hv.w, wi##i.w, ai); \
        af = fmaf(hv.x, wf##i.x, af); af = fmaf(hv.y, wf##i.y, af); \
        af = fmaf(hv.z, wf##i.z, af); af = fmaf(hv.w, wf##i.w, af); \
        ag = fmaf(hv.x, wg##i.x, ag); ag = fmaf(hv.y, wg##i.y, ag); \
        ag = fmaf(hv.z, wg##i.z, ag); ag = fmaf(hv.w, wg##i.w, ag); \
        ao = fmaf(hv.x, wo##i.x, ao); ao = fmaf(hv.y, wo##i.y, ao); \
        ao = fmaf(hv.z, wo##i.z, ao); ao = fmaf(hv.w, wo##i.w, ao); }
    REP8(DOT4)
    ai += __shfl_xor(ai, 1, 64); af += __shfl_xor(af, 1, 64);
    ag += __shfl_xor(ag, 1, 64); ao += __shfl_xor(ao, 1, 64);
    ai += __shfl_xor(ai, 2, 64); af += __shfl_xor(af, 2, 64);
    ag += __shfl_xor(ag, 2, 64); ao += __shfl_xor(ao, 2, 64);
    const float iv0 = sigmoid_f(ai + cbi);
    const float fv0 = sigmoid_f(af + cbf);
    const float gv0 = tanh_f  (ag + cbg);
    const float ov0 = sigmoid_f(ao + cbo);
    float c = iv0 * gv0;                 // c_prev = 0
    const float hn0 = ov0 * tanh_f(c);
    if (q == 0) hist[hword] = hn0;       // slot 0 = state 1
    __syncthreads();

    // ---- asm operand prep ----
    const unsigned histB = (unsigned)(unsigned long long)(&hist[0]);
    const unsigned vR0 = histB + 144u * (unsigned)q;           // slot0 quarter
    const unsigned hW0 = histB + 4u * (unsigned)hword;         // write(slot0); early +576 -> slot t
    const unsigned vD0 = (unsigned)(144 * q - 4 * hword);      // read(t) - write(t)
    const unsigned fR0 = histB + 576u * (unsigned)m + 144u * (unsigned)q;
    const unsigned jO0 = 1024u * (unsigned)m;                  // out j*1024
    const unsigned vO0 = 4u * (unsigned)batch;                 // out[0] byte
    // permuted weight-row byte offsets: slot p <- row (m + 128*(q^p))
    const unsigned off0 = (unsigned)((m + 128 * (q    )) * 512 + q * 128);
    const unsigned off1 = (unsigned)((m + 128 * (q ^ 1)) * 512 + q * 128);
    const unsigned off2 = (unsigned)((m + 128 * (q ^ 2)) * 512 + q * 128);
    const unsigned off3 = (unsigned)((m + 128 * (q ^ 3)) * 512 + q * 128);
    const unsigned offL = (unsigned)(q * 128);

    asm volatile(
        // ---------------- prologue: fixed-reg setup ----------------
        "v_mov_b32 v220, %[b0]\n\t"
        "v_mov_b32 v221, 0\n\t"
        "v_mov_b32 v222, %[b1]\n\t"
        "v_mov_b32 v223, 0\n\t"
        "v_mov_b32 v224, %[b2]\n\t"
        "v_mov_b32 v225, 0\n\t"
        "v_mov_b32 v226, %[b3]\n\t"
        "v_mov_b32 v227, 0\n\t"
        "v_mov_b32 v185, %[blin]\n\t"
        "v_mov_b32 v168, %[c0]\n\t"
        "v_mov_b32 v172, %[vR]\n\t"
        "v_mov_b32 v174, %[hW]\n\t"
        "v_mov_b32 v186, %[vD]\n\t"
        "v_mov_b32 v184, %[fR]\n\t"
        "v_mov_b32 v171, %[jO]\n\t"
        "v_mov_b32 v176, %[vO]\n\t"
        // q==0 store mask (lanes 0,4,8,...) -> s[26:27]
        "s_mov_b32 s26, 0x11111111\n\t"
        "s_mov_b32 s27, 0x11111111\n\t"
        // weights: 8x dwordx4 per slot into fixed quads (gate-permuted rows)
        "global_load_dwordx4 v[32:35], %[off0], %[whh] offset:0\n\t"
        "global_load_dwordx4 v[36:39], %[off0], %[whh] offset:16\n\t"
        "global_load_dwordx4 v[40:43], %[off0], %[whh] offset:32\n\t"
        "global_load_dwordx4 v[44:47], %[off0], %[whh] offset:48\n\t"
        "global_load_dwordx4 v[48:51], %[off0], %[whh] offset:64\n\t"
        "global_load_dwordx4 v[52:55], %[off0], %[whh] offset:80\n\t"
        "global_load_dwordx4 v[56:59], %[off0], %[whh] offset:96\n\t"
        "global_load_dwordx4 v[60:63], %[off0], %[whh] offset:112\n\t"
        "global_load_dwordx4 v[64:67], %[off1], %[whh] offset:0\n\t"
        "global_load_dwordx4 v[68:71], %[off1], %[whh] offset:16\n\t"
        "global_load_dwordx4 v[72:75], %[off1], %[whh] offset:32\n\t"
        "global_load_dwordx4 v[76:79], %[off1], %[whh] offset:48\n\t"
        "global_load_dwordx4 v[80:83], %[off1], %[whh] offset:64\n\t"
        "global_load_dwordx4 v[84:87], %[off1], %[whh] offset:80\n\t"
        "global_load_dwordx4 v[88:91], %[off1], %[whh] offset:96\n\t"
        "global_load_dwordx4 v[92:95], %[off1], %[whh] offset:112\n\t"
        "global_load_dwordx4 v[96:99], %[off2], %[whh] offset:0\n\t"
        "global_load_dwordx4 v[100:103], %[off2], %[whh] offset:16\n\t"
        "global_load_dwordx4 v[104:107], %[off2], %[whh] offset:32\n\t"
        "global_load_dwordx4 v[108:111], %[off2], %[whh] offset:48\n\t"
        "global_load_dwordx4 v[112:115], %[off2], %[whh] offset:64\n\t"
        "global_load_dwordx4 v[116:119], %[off2], %[whh] offset:80\n\t"
        "global_load_dwordx4 v[120:123], %[off2], %[whh] offset:96\n\t"
        "global_load_dwordx4 v[124:127], %[off2], %[whh] offset:112\n\t"
        "global_load_dwordx4 v[128:131], %[off3], %[whh] offset:0\n\t"
        "global_load_dwordx4 v[132:135], %[off3], %[whh] offset:16\n\t"
        "global_load_dwordx4 v[136:139], %[off3], %[whh] offset:32\n\t"
        "global_load_dwordx4 v[140:143], %[off3], %[whh] offset:48\n\t"
        "global_load_dwordx4 v[144:147], %[off3], %[whh] offset:64\n\t"
        "global_load_dwordx4 v[148:151], %[off3], %[whh] offset:80\n\t"
        "global_load_dwordx4 v[152:155], %[off3], %[whh] offset:96\n\t"
        "global_load_dwordx4 v[156:159], %[off3], %[whh] offset:112\n\t"
        // W_lin quarter-slice -> persistent v[188:219]
        "global_load_dwordx4 v[188:191], %[offL], %[wlin] offset:0\n\t"
        "global_load_dwordx4 v[192:195], %[offL], %[wlin] offset:16\n\t"
        "global_load_dwordx4 v[196:199], %[offL], %[wlin] offset:32\n\t"
        "global_load_dwordx4 v[200:203], %[offL], %[wlin] offset:48\n\t"
        "global_load_dwordx4 v[204:207], %[offL], %[wlin] offset:64\n\t"
        "global_load_dwordx4 v[208:211], %[offL], %[wlin] offset:80\n\t"
        "global_load_dwordx4 v[212:215], %[offL], %[wlin] offset:96\n\t"
        "global_load_dwordx4 v[216:219], %[offL], %[wlin] offset:112\n\t"
        "s_waitcnt vmcnt(0)\n\t"
        // fold: W'[slot p] = W + wih(p^q) * W_lin, then pre-scale by that
        // gate's exp2 constant (per-lane VGPR scale).
        ".set K_I, 0\n"
        ".rept 32\n"
        " v_fma_f32 v[32+K_I],  %[wA], v[188+K_I], v[32+K_I]\n"
        " v_fma_f32 v[64+K_I],  %[wB], v[188+K_I], v[64+K_I]\n"
        " v_fma_f32 v[96+K_I],  %[wC], v[188+K_I], v[96+K_I]\n"
        " v_fma_f32 v[128+K_I], %[wD], v[188+K_I], v[128+K_I]\n"
        " .set K_I, K_I+1\n"
        ".endr\n"
        ".set K_I, 0\n"
        ".rept 32\n"
        " v_mul_f32 v[32+K_I],  %[sc0], v[32+K_I]\n"
        " v_mul_f32 v[64+K_I],  %[sc1], v[64+K_I]\n"
        " v_mul_f32 v[96+K_I],  %[sc2], v[96+K_I]\n"
        " v_mul_f32 v[128+K_I], %[sc3], v[128+K_I]\n"
        " .set K_I, K_I+1\n"
        ".endr\n"
        "s_movk_i32 s24, 1\n\t"
        // ---------------- main loop: t = 1 .. 2047 ----------------
        "1:\n\t"
        // h quarter: 8x b128 broadcast reads from slot t-1
        "ds_read_b128 v[0:3],   v172\n\t"
        "ds_read_b128 v[4:7],   v172 offset:16\n\t"
        "ds_read_b128 v[8:11],  v172 offset:32\n\t"
        "ds_read_b128 v[12:15], v172 offset:48\n\t"
        "ds_read_b128 v[16:19], v172 offset:64\n\t"
        "ds_read_b128 v[20:23], v172 offset:80\n\t"
        "ds_read_b128 v[24:27], v172 offset:96\n\t"
        "ds_read_b128 v[28:31], v172 offset:112\n\t"
        // ---- packed GEMV: pairs 0-3 once reads 0-1 land ----
        "s_waitcnt lgkmcnt(6)\n\t"
        "v_pk_fma_f32 v[160:161], v[0:1], v[32:33], v[220:221]\n\t"
        "v_pk_fma_f32 v[162:163], v[0:1], v[64:65], v[222:223]\n\t"
        "v_pk_fma_f32 v[164:165], v[0:1], v[96:97], v[224:225]\n\t"
        "v_pk_fma_f32 v[166:167], v[0:1], v[128:129], v[226:227]\n\t"
        ".set K_I, 2\n"
        ".rept 3\n"
        " v_pk_fma_f32 v[160:161], v[K_I:K_I+1], v[32+K_I:33+K_I], v[160:161]\n"
        " v_pk_fma_f32 v[162:163], v[K_I:K_I+1], v[64+K_I:65+K_I], v[162:163]\n"
        " v_pk_fma_f32 v[164:165], v[K_I:K_I+1], v[96+K_I:97+K_I], v[164:165]\n"
        " v_pk_fma_f32 v[166:167], v[K_I:K_I+1], v[128+K_I:129+K_I], v[166:167]\n"
        " .set K_I, K_I+2\n"
        ".endr\n"
        "s_waitcnt lgkmcnt(4)\n\t"
        ".rept 4\n"
        " v_pk_fma_f32 v[160:161], v[K_I:K_I+1], v[32+K_I:33+K_I], v[160:161]\n"
        " v_pk_fma_f32 v[162:163], v[K_I:K_I+1], v[64+K_I:65+K_I], v[162:163]\n"
        " v_pk_fma_f32 v[164:165], v[K_I:K_I+1], v[96+K_I:97+K_I], v[164:165]\n"
        " v_pk_fma_f32 v[166:167], v[K_I:K_I+1], v[128+K_I:129+K_I], v[166:167]\n"
        " .set K_I, K_I+2\n"
        ".endr\n"
        "s_waitcnt lgkmcnt(2)\n\t"
        ".rept 4\n"
        " v_pk_fma_f32 v[160:161], v[K_I:K_I+1], v[32+K_I:33+K_I], v[160:161]\n"
        " v_pk_fma_f32 v[162:163], v[K_I:K_I+1], v[64+K_I:65+K_I], v[162:163]\n"
        " v_pk_fma_f32 v[164:165], v[K_I:K_I+1], v[96+K_I:97+K_I], v[164:165]\n"
        " v_pk_fma_f32 v[166:167], v[K_I:K_I+1], v[128+K_I:129+K_I], v[166:167]\n"
        " .set K_I, K_I+2\n"
        ".endr\n"
        "s_waitcnt lgkmcnt(0)\n\t"
        ".rept 4\n"
        " v_pk_fma_f32 v[160:161], v[K_I:K_I+1], v[32+K_I:33+K_I], v[160:161]\n"
        " v_pk_fma_f32 v[162:163], v[K_I:K_I+1], v[64+K_I:65+K_I], v[162:163]\n"
        " v_pk_fma_f32 v[164:165], v[K_I:K_I+1], v[96+K_I:97+K_I], v[164:165]\n"
        " v_pk_fma_f32 v[166:167], v[K_I:K_I+1], v[128+K_I:129+K_I], v[166:167]\n"
        " .set K_I, K_I+2\n"
        ".endr\n"
        // ---- collapse lo+hi: slot sums S0..S3 (slot p = gate p^q) ----
        "v_add_f32 v160, v160, v161\n\t"
        "v_add_f32 v161, v162, v163\n\t"
        "v_add_f32 v164, v164, v165\n\t"
        "v_add_f32 v165, v166, v167\n\t"
        // ---- 3-DPP gate butterfly: v160 <- FULL sum of gate q on lane q ----
        "s_nop 1\n\t"
        "v_add_f32_dpp v160, v161, v160 quad_perm:[1,0,3,2] row_mask:0xf bank_mask:0xf\n\t"
        "v_add_f32_dpp v164, v165, v164 quad_perm:[1,0,3,2] row_mask:0xf bank_mask:0xf\n\t"
        // ptr advance fills the DPP->DPP gap: v174 -> write(t), v172 -> read(t)
        "v_add_u32 v174, 0x240, v174\n\t"
        "v_add_u32 v172, v174, v186\n\t"
        "s_nop 1\n\t"
        "v_add_f32_dpp v160, v164, v160 quad_perm:[2,3,0,1] row_mask:0xf bank_mask:0xf\n\t"
        // ---- single activation path (values pre-scaled for exp2) ----
        "s_nop 3\n\t"
        "v_exp_f32 v160, v160\n\t"
        "s_nop 1\n\t"
        "v_add_f32 v160, 1.0, v160\n\t"
        "v_rcp_f32 v160, v160\n\t"
        "s_nop 1\n\t"
        "v_fma_f32 v166, %[ca], v160, %[cb]\n\t"   // a = sigmoid / tanh of gate q
        // ---- quad redistribute: t1 = i*g (lane0), t2 = f, t3 = o ----
        "s_nop 3\n\t"
        "v_mul_f32_dpp v161, v166, v166 quad_perm:[2,3,0,1] row_mask:0xf bank_mask:0xf\n\t"
        "v_mov_b32_dpp v162, v166 quad_perm:[1,0,3,2] row_mask:0xf bank_mask:0xf\n\t"
        "v_mov_b32_dpp v165, v166 quad_perm:[3,3,3,3] row_mask:0xf bank_mask:0xf\n\t"
        "s_nop 2\n\t"
        "v_fma_f32 v168, v162, v168, v161\n\t"     // c = f*c + i*g  (lane0 exact)
        // tanh(c) with explicit wait states
        "v_mul_f32 v163, 0x4038aa3b, v168\n\t"
        "v_exp_f32 v163, v163\n\t"
        "s_nop 1\n\t"
        "v_add_f32 v163, 1.0, v163\n\t"
        "v_rcp_f32 v163, v163\n\t"
        "s_nop 1\n\t"
        "v_fma_f32 v163, -2.0, v163, 1.0\n\t"
        "v_mul_f32 v169, v165, v163\n\t"           // hn = o * tanh(c)
        // publish h into ring slot t (q==0 lanes; v174 already advanced)
        "s_mov_b64 s[22:23], exec\n\t"
        "s_mov_b64 exec, s[26:27]\n\t"
        "ds_write_b32 v174, v169\n\t"
        "s_mov_b64 exec, s[22:23]\n\t"
        "s_waitcnt lgkmcnt(0)\n\t"
        "s_barrier\n\t"
        // ---- flush every 128 steps: out[...] = hist[j].WL + blin ----
        "s_and_b32 s20, s24, 127\n\t"
        "s_cmp_lg_u32 s20, 127\n\t"
        "s_cbranch_scc1 3f\n\t"
        "v_add_u32 v174, 0xfffee000, v174\n\t"   // write base wrap: -73728
        "ds_read_b128 v[0:3],   v184\n\t"
        "ds_read_b128 v[4:7],   v184 offset:16\n\t"
        "ds_read_b128 v[8:11],  v184 offset:32\n\t"
        "ds_read_b128 v[12:15], v184 offset:48\n\t"
        "ds_read_b128 v[16:19], v184 offset:64\n\t"
        "ds_read_b128 v[20:23], v184 offset:80\n\t"
        "ds_read_b128 v[24:27], v184 offset:96\n\t"
        "ds_read_b128 v[28:31], v184 offset:112\n\t"
        "v_mov_b32 v164, 0\n\t"
        "s_waitcnt lgkmcnt(0)\n\t"
        ".set K_I, 0\n"
        ".rept 32\n"
        " v_fma_f32 v164, v[0+K_I], v[188+K_I], v164\n"
        " .set K_I, K_I+1\n"
        ".endr\n"
        "s_nop 1\n\t"
        "v_add_f32_dpp v164, v164, v164 quad_perm:[1,0,3,2] row_mask:0xf bank_mask:0xf\n\t"
        "s_nop 1\n\t"
        "v_add_f32_dpp v164, v164, v164 quad_perm:[2,3,0,1] row_mask:0xf bank_mask:0xf\n\t"
        "v_add_f32 v164, v164, v185\n\t"         // + b_lin
        "v_add_u32 v170, v176, v171\n\t"         // out byte = base + j*1024
        "s_mov_b64 s[22:23], exec\n\t"
        "s_mov_b64 exec, s[26:27]\n\t"
        "global_store_dword v170, v164, %[outp]\n\t"
        "s_mov_b64 exec, s[22:23]\n\t"
        "v_add_u32 v176, 0x20000, v176\n\t"      // out base += 128*256*4
        "s_barrier\n\t"                           // protect hist vs next iter
        "3:\n\t"
        "s_add_i32 s24, s24, 1\n\t"
        "s_cmp_lt_i32 s24, 2048\n\t"
        "s_cbranch_scc1 1b\n\t"
        :
        : [off0]"v"(off0), [off1]"v"(off1), [off2]"v"(off2), [off3]"v"(off3),
          [offL]"v"(offL), [whh]"s"(W_hh), [wlin]"s"(W_lin), [outp]"s"(out),
          [wA]"v"(wihA), [wB]"v"(wihB), [wC]"v"(wihC), [wD]"v"(wihD),
          [b0]"v"(b0s), [b1]"v"(b1s), [b2]"v"(b2s), [b3]"v"(b3s),
          [sc0]"v"(sc0), [sc1]"v"(sc1), [sc2]"v"(sc2), [sc3]"v"(sc3),
          [ca]"v"(caq), [cb]"v"(cbq),
          [blin]"s"(blin), [c0]"v"(c),
          [vR]"v"(vR0), [hW]"v"(hW0), [vD]"v"(vD0), [fR]"v"(fR0),
          [jO]"v"(jO0), [vO]"s"(vO0)
        : "memory", "scc", "vcc", "s20","s21","s22","s23","s24","s25","s26","s27",
          "v0","v1","v2","v3","v4","v5","v6","v7","v8","v9",
          "v10","v11","v12","v13","v14","v15","v16","v17","v18","v19",
          "v20","v21","v22","v23","v24","v25","v26","v27","v28","v29",
          "v30","v31","v32","v33","v34","v35","v36","v37","v38","v39",
          "v40","v41","v42","v43","v44","v45","v46","v47","v48","v49",
          "v50","v51","v52","v53","v54","v55","v56","v57","v58","v59",
          "v60","v61","v62","v63","v64","v65","v66","v67","v68","v69",
          "v70","v71","v72","v73","v74","v75","v76","v77","v78","v79",
          "v80","v81","v82","v83","v84","v85","v86","v87","v88","v89",
          "v90","v91","v92","v93","v94","v95","v96","v97","v98","v99",
          "v100","v101","v102","v103","v104","v105","v106","v107","v108","v109",
          "v110","v111","v112","v113","v114","v115","v116","v117","v118","v119",
          "v120","v121","v122","v123","v124","v125","v126","v127","v128","v129",
          "v130","v131","v132","v133","v134","v135","v136","v137","v138","v139",
          "v140","v141","v142","v143","v144","v145","v146","v147","v148","v149",
          "v150","v151","v152","v153","v154","v155","v156","v157","v158","v159",
          "v160","v161","v162","v163","v164","v165","v166","v167","v168","v169",
          "v170","v171","v172","v173","v174","v175","v176","v177","v178","v179",
          "v180","v181","v182","v183","v184","v185","v186","v187","v188","v189",
          "v190","v191","v192","v193","v194","v195","v196","v197","v198","v199",
          "v200","v201","v202","v203","v204","v205","v206","v207","v208","v209",
          "v210","v211","v212","v213","v214","v215","v216","v217","v218","v219",
          "v220","v221","v222","v223","v224","v225","v226","v227");
    // no C epilogue: flush k=15 covers out[1920..2047]
}

extern "C" void kernel_launch(void* const* d_in, const int* in_sizes, int n_in,
                              void* d_out, int out_size, void* d_ws, size_t ws_size,
                              hipStream_t stream) {
    // inputs: 0 input (unused), 1 label, 2 h0, 3 W_ih, 4 W_hh,
    //         5 b_ih, 6 b_hh, 7 W_lin, 8 b_lin
    const int*   label = (const int*)  d_in[1];
    const float* h0    = (const float*)d_in[2];
    const float* W_ih  = (const float*)d_in[3];
    const float* W_hh  = (const float*)d_in[4];
    const float* b_ih  = (const float*)d_in[5];
    const float* b_hh  = (const float*)d_in[6];
    const float* W_lin = (const float*)d_in[7];
    const float* b_lin = (const float*)d_in[8];
    float* out = (float*)d_out;

    lstm_seq_kernel<<<dim3(BATCH), dim3(512), 0, stream>>>(
        label, h0, W_ih, W_hh, b_ih, b_hh, W_lin, b_lin, out);
}